// Round 4
// baseline (344.488 us; speedup 1.0000x reference)
//
#include <hip/hip_runtime.h>
#include <stdint.h>

typedef unsigned short u16;
typedef __bf16 bf16x8 __attribute__((ext_vector_type(8)));
typedef float f32x4 __attribute__((ext_vector_type(4)));

#define T_SEQ 4096
#define DMODEL 1024

__device__ __forceinline__ float bf2f(u16 x) {
  union { uint32_t u; float f; } v; v.u = ((uint32_t)x) << 16; return v.f;
}
__device__ __forceinline__ u16 f2bf(float f) {
  union { float f; uint32_t u; } v; v.f = f;
  return (u16)((v.u + 0x7FFFu + ((v.u >> 16) & 1u)) >> 16);  // RNE, finite inputs only
}
__device__ __forceinline__ float fexp2(float x) {
#if __has_builtin(__builtin_amdgcn_exp2f)
  return __builtin_amdgcn_exp2f(x);
#else
  return __expf(x * 0.6931471805599453f);
#endif
}
// pack two f32 -> packed bf16x2 (lo in low16). HW cvt if available, else
// round-half-up + v_perm (error <= 1 ulp on ties; P in [0,1], slack is huge).
__device__ __forceinline__ uint32_t pack_bf16(float lo, float hi) {
#if __has_builtin(__builtin_amdgcn_cvt_pk_bf16_f32)
  typedef __bf16 bf16x2_t __attribute__((ext_vector_type(2)));
  union { bf16x2_t v; uint32_t u; } c;
  c.v = __builtin_amdgcn_cvt_pk_bf16_f32(lo, hi);
  return c.u;
#else
  union { float f; uint32_t u; } a, b;
  a.f = lo; b.f = hi;
  return __builtin_amdgcn_perm(b.u + 0x8000u, a.u + 0x8000u, 0x07060302u);
#endif
}
// async global->LDS, 16B/lane. LDS dest = wave-uniform base + lane*16 (guide §5 caveat).
__device__ __forceinline__ void async16(void* lds, const void* g) {
  __builtin_amdgcn_global_load_lds(
      (__attribute__((address_space(1))) void*)const_cast<void*>(g),
      (__attribute__((address_space(3))) void*)lds, 16, 0, 0);
}
__device__ __forceinline__ void storeC(u16* C, size_t i, float v) { C[i] = f2bf(v); }
__device__ __forceinline__ void storeC(float* C, size_t i, float v) { C[i] = v; }

// ---------------- fp32 -> bf16 elementwise copy ----------------
__global__ void __launch_bounds__(256) f2b_copy(const float* __restrict__ in,
                                                u16* __restrict__ out, int n) {
  int idx = (blockIdx.x * 256 + threadIdx.x) * 4;
  if (idx >= n) return;
  float4 v = *(const float4*)(in + idx);
  union { u16 s[4]; uint2 q; } b;
  b.s[0] = f2bf(v.x); b.s[1] = f2bf(v.y); b.s[2] = f2bf(v.z); b.s[3] = f2bf(v.w);
  *(uint2*)(out + idx) = b.q;
}

// ---------------- fp32 [K][N] -> bf16 [N][K] tiled transpose ----------------
__global__ void __launch_bounds__(256) wtrans(const float* __restrict__ in,
                                              u16* __restrict__ out, int K, int N) {
  __shared__ float tile[64][65];
  const int n0 = blockIdx.x * 64, k0 = blockIdx.y * 64;
  const int tid = threadIdx.x;
  const int r = tid >> 2, c = (tid & 3) * 16;
#pragma unroll
  for (int j = 0; j < 4; ++j) {
    float4 v = *(const float4*)&in[(size_t)(k0 + r) * N + n0 + c + j * 4];
    tile[r][c + j * 4 + 0] = v.x; tile[r][c + j * 4 + 1] = v.y;
    tile[r][c + j * 4 + 2] = v.z; tile[r][c + j * 4 + 3] = v.w;
  }
  __syncthreads();
  union { u16 s[16]; uint4 q[2]; } buf;
#pragma unroll
  for (int j = 0; j < 16; ++j) buf.s[j] = f2bf(tile[c + j][r]);
  u16* dst = out + (size_t)(n0 + r) * K + k0 + c;
  *(uint4*)(dst) = buf.q[0];
  *(uint4*)(dst + 8) = buf.q[1];
}

// ---------------- bf16 V slice transpose: QKV[t][1280+h*64+d] -> Vt[h][d][t] ----------------
__global__ void __launch_bounds__(256) vtrans(const u16* __restrict__ qkv,
                                              u16* __restrict__ Vt) {
  __shared__ u16 tile[64][65];
  const int t0 = blockIdx.x * 64, h = blockIdx.y;
  const int tid = threadIdx.x;
  const int r = tid >> 2, q4 = (tid & 3) * 16;
  const u16* src = qkv + (size_t)(t0 + r) * 1536 + 1280 + h * 64 + q4;
  union { u16 s[16]; uint4 q[2]; } buf;
  buf.q[0] = *(const uint4*)(src);
  buf.q[1] = *(const uint4*)(src + 8);
#pragma unroll
  for (int j = 0; j < 16; ++j) tile[r][q4 + j] = buf.s[j];
  __syncthreads();
#pragma unroll
  for (int j = 0; j < 16; ++j) buf.s[j] = tile[q4 + j][r];
  u16* dst = Vt + ((size_t)h * 64 + r) * T_SEQ + t0 + q4;
  *(uint4*)(dst) = buf.q[0];
  *(uint4*)(dst + 8) = buf.q[1];
}

// ---------------- RoPE: QKV[t][1536] -> Q[16][T][64] (x 0.125*log2e folded), K[4][T][64] ----
__global__ void __launch_bounds__(256) rope_qk(const u16* __restrict__ qkv,
                                               u16* __restrict__ Q, u16* __restrict__ Ko) {
  const int t = blockIdx.x;
  const int tid = threadIdx.x;
  const int i = tid & 31;
  const float ang = (float)t * powf(10000.f, -(float)i * (1.f / 32.f));
  float s, c;
  sincosf(ang, &s, &c);
  const u16* row = qkv + (size_t)t * 1536;
  const float QS = 0.125f * 1.4426950408889634f;
  const float cq = c * QS, sq = s * QS;
#pragma unroll
  for (int it = 0; it < 2; ++it) {
    int h = (tid >> 5) + it * 8;
    float x1 = bf2f(row[h * 64 + i]);
    float x2 = bf2f(row[h * 64 + 32 + i]);
    size_t o = ((size_t)h * T_SEQ + t) * 64 + i;
    Q[o] = f2bf(x1 * cq - x2 * sq);
    Q[o + 32] = f2bf(x2 * cq + x1 * sq);
  }
  if (tid < 128) {
    int h = tid >> 5;
    float x1 = bf2f(row[1024 + h * 64 + i]);
    float x2 = bf2f(row[1024 + h * 64 + 32 + i]);
    size_t o = ((size_t)h * T_SEQ + t) * 64 + i;
    Ko[o] = f2bf(x1 * c - x2 * s);
    Ko[o + 32] = f2bf(x2 * c + x1 * s);
  }
}

// ---------------- bf16 GEMM: C[M][N] = A[M][K] @ Bt[N][K]^T ----------------
template <int AM, int ACT, typename OutT>
__global__ void __launch_bounds__(256) gemm_bt(const u16* __restrict__ A,
                                               const u16* __restrict__ Bt,
                                               OutT* __restrict__ C,
                                               int M, int N, int K) {
  __shared__ u16 sA[AM * 32][64];
  __shared__ u16 sB[128][64];
  const int tid = threadIdx.x;
  const int w = tid >> 6, lane = tid & 63;
  const int g = lane >> 4, l15 = lane & 15;
  const int r8 = lane >> 3, c8 = lane & 7;
  const int bm = blockIdx.y * (AM * 32), bn = blockIdx.x * 128;

  f32x4 acc[AM][4];
#pragma unroll
  for (int i = 0; i < AM; ++i)
#pragma unroll
    for (int j = 0; j < 4; ++j) acc[i][j] = (f32x4){0.f, 0.f, 0.f, 0.f};

  const u16* Ag = A + (size_t)(bm + w * (AM * 8) + r8) * K + (c8 ^ r8) * 8;
  const u16* Bg = Bt + (size_t)(bn + w * 32 + r8) * K + (c8 ^ r8) * 8;
  const int mrow = (w >> 1) * (AM * 16), ncol = (w & 1) * 64;
  const int swz = l15 & 7;

  for (int k0 = 0; k0 < K; k0 += 64) {
#pragma unroll
    for (int t = 0; t < AM; ++t)
      async16(&sA[w * (AM * 8) + t * 8][0], Ag + (size_t)(t * 8) * K + k0);
#pragma unroll
    for (int t = 0; t < 4; ++t)
      async16(&sB[w * 32 + t * 8][0], Bg + (size_t)(t * 8) * K + k0);
    __syncthreads();
#pragma unroll
    for (int kk = 0; kk < 2; ++kk) {
      const int cb = ((kk * 4 + g) ^ swz) * 8;
      bf16x8 a[AM], b[4];
#pragma unroll
      for (int i = 0; i < AM; ++i) a[i] = *(const bf16x8*)&sA[mrow + i * 16 + l15][cb];
#pragma unroll
      for (int i = 0; i < 4; ++i) b[i] = *(const bf16x8*)&sB[ncol + i * 16 + l15][cb];
#pragma unroll
      for (int mi = 0; mi < AM; ++mi)
#pragma unroll
        for (int ni = 0; ni < 4; ++ni)
          acc[mi][ni] = __builtin_amdgcn_mfma_f32_16x16x32_bf16(a[mi], b[ni], acc[mi][ni], 0, 0, 0);
    }
    __syncthreads();
  }
#pragma unroll
  for (int mi = 0; mi < AM; ++mi)
#pragma unroll
    for (int ni = 0; ni < 4; ++ni)
#pragma unroll
      for (int r = 0; r < 4; ++r) {
        int row = bm + mrow + mi * 16 + g * 4 + r;
        int col = bn + ncol + ni * 16 + l15;
        float v = acc[mi][ni][r];
        if (ACT == 1) v = v / (1.f + __expf(-v));  // SiLU
        storeC(C, (size_t)row * N + col, v);
      }
}

// ---------------- Flash attention (causal, GQA 16q/4kv, D=64) ----------------
// 128-row q-tile PAIRS (t0=pr, t1=31-pr), grid 16x16 = 256 = 1 block/CU.
// Per kv-iter each wave covers 64 q (2 halves x 2 mi of 16) so every kf/vf
// LDS fragment read feeds 4 MFMAs (halves LDS traffic vs 64-row pairs).
// S computed transposed (mfma(kf,qf) -> D[kv][q]); P round-trips LDS with a
// kt^(l15&3) block swizzle (sP unpadded, total LDS exactly 64 KB).
// Row sums via ones-MFMA (lacc lands in C-layout -> zero-shuffle epilogue,
// and l is exactly the sum of the rounded P used in PV).
// No-max softmax: Q pre-scaled by 0.125*log2e, p = exp2(s) can't overflow.
__global__ void __launch_bounds__(256, 1) attn(const u16* __restrict__ Q,
                                               const u16* __restrict__ K,
                                               const u16* __restrict__ Vt,
                                               u16* __restrict__ O) {
  __shared__ u16 sK[2][64][64];
  __shared__ u16 sV[2][64][64];     // sV[b][d][kv]
  __shared__ u16 sP[4][64][64];     // [wave][half*32+mi*16+q16][kv-swizzled]
  const int pr = blockIdx.x;
  const int h = blockIdx.y;
  const int kvh = h >> 2;
  const int tid = threadIdx.x;
  const int w = tid >> 6, lane = tid & 63;
  const int g = lane >> 4, l15 = lane & 15;
  const int r8 = lane >> 3, c8 = lane & 7;
  const int swz = l15 & 7, d3 = l15 & 3;
  const int t0 = pr, t1 = 31 - pr;

  // Q fragments straight from global (B-operand: n=q=l15, k=d)
  bf16x8 qf[2][2][2];
  {
    const u16* Qh = Q + (size_t)h * T_SEQ * 64;
#pragma unroll
    for (int half = 0; half < 2; ++half)
#pragma unroll
      for (int mi = 0; mi < 2; ++mi) {
        const int q = (half ? t1 : t0) * 128 + w * 32 + mi * 16 + l15;
#pragma unroll
        for (int kk = 0; kk < 2; ++kk)
          qf[half][mi][kk] = *(const bf16x8*)(Qh + (size_t)q * 64 + (kk * 4 + g) * 8);
      }
  }

  f32x4 oacc[2][2][4];
  f32x4 lacc[2][2];
#pragma unroll
  for (int half = 0; half < 2; ++half)
#pragma unroll
    for (int mi = 0; mi < 2; ++mi) {
      lacc[half][mi] = (f32x4){0.f, 0.f, 0.f, 0.f};
#pragma unroll
      for (int nd = 0; nd < 4; ++nd) oacc[half][mi][nd] = (f32x4){0.f, 0.f, 0.f, 0.f};
    }

  bf16x8 ONES;
  {
    union { u16 s[8]; bf16x8 v; } o;
#pragma unroll
    for (int i = 0; i < 8; ++i) o.s[i] = 0x3F80;  // bf16 1.0
    ONES = o.v;
  }

  const u16* Kg = K + ((size_t)kvh * T_SEQ + w * 16 + r8) * 64 + (c8 ^ r8) * 8;
  const u16* Vg = Vt + ((size_t)kvh * 64 + w * 16 + r8) * T_SEQ + (c8 ^ r8) * 8;

#define STAGE(J, B)                                                     \
  {                                                                     \
    const int kv0_ = (J) * 64;                                          \
    async16(&sK[B][w * 16 + 0][0], Kg + (size_t)kv0_ * 64);             \
    async16(&sK[B][w * 16 + 8][0], Kg + (size_t)(kv0_ + 8) * 64);       \
    async16(&sV[B][w * 16 + 0][0], Vg + kv0_);                          \
    async16(&sV[B][w * 16 + 8][0], Vg + (size_t)8 * T_SEQ + kv0_);      \
  }

#define BODY(B, ACT0, M0, M1, OFF)                                                \
  {                                                                               \
    const int b_ = (B);                                                           \
    f32x4 s1[2][4], s0[2][4];                                                     \
    _Pragma("unroll") for (int mi = 0; mi < 2; ++mi)                              \
    _Pragma("unroll") for (int kt = 0; kt < 4; ++kt) {                            \
      s1[mi][kt] = (f32x4){0.f, 0.f, 0.f, 0.f};                                   \
      if (ACT0) s0[mi][kt] = (f32x4){0.f, 0.f, 0.f, 0.f};                         \
    }                                                                             \
    _Pragma("unroll") for (int kt = 0; kt < 4; ++kt)                              \
    _Pragma("unroll") for (int kk = 0; kk < 2; ++kk) {                            \
      bf16x8 kf = *(const bf16x8*)&sK[b_][kt * 16 + l15][((kk * 4 + g) ^ swz) * 8]; \
      _Pragma("unroll") for (int mi = 0; mi < 2; ++mi) {                          \
        s1[mi][kt] = __builtin_amdgcn_mfma_f32_16x16x32_bf16(kf, qf[1][mi][kk], s1[mi][kt], 0, 0, 0); \
        if (ACT0)                                                                 \
          s0[mi][kt] = __builtin_amdgcn_mfma_f32_16x16x32_bf16(kf, qf[0][mi][kk], s0[mi][kt], 0, 0, 0); \
      }                                                                           \
    }                                                                             \
    _Pragma("unroll") for (int mi = 0; mi < 2; ++mi) {                            \
      const int thr_ = w * 32 + mi * 16 + l15 - (OFF);                            \
      _Pragma("unroll") for (int kt = 0; kt < 4; ++kt) {                          \
        float p_[4];                                                              \
        _Pragma("unroll") for (int r = 0; r < 4; ++r) {                           \
          float p = fexp2(s1[mi][kt][r]);                                         \
          if (M1 && (kt * 16 + g * 4 + r > thr_)) p = 0.f;                        \
          p_[r] = p;                                                              \
        }                                                                         \
        uint2 pk;                                                                 \
        pk.x = pack_bf16(p_[0], p_[1]);                                           \
        pk.y = pack_bf16(p_[2], p_[3]);                                           \
        *(uint2*)&sP[w][32 + mi * 16 + l15][(kt ^ d3) * 16 + g * 4] = pk;         \
      }                                                                           \
      if (ACT0) {                                                                 \
        _Pragma("unroll") for (int kt = 0; kt < 4; ++kt) {                        \
          float p_[4];                                                            \
          _Pragma("unroll") for (int r = 0; r < 4; ++r) {                         \
            float p = fexp2(s0[mi][kt][r]);                                       \
            if (M0 && (kt * 16 + g * 4 + r > thr_)) p = 0.f;                      \
            p_[r] = p;                                                            \
          }                                                                       \
          uint2 pk;                                                               \
          pk.x = pack_bf16(p_[0], p_[1]);                                         \
          pk.y = pack_bf16(p_[2], p_[3]);                                         \
          *(uint2*)&sP[w][mi * 16 + l15][(kt ^ d3) * 16 + g * 4] = pk;            \
        }                                                                         \
      }                                                                           \
    }                                                                             \
    __builtin_amdgcn_wave_barrier(); /* sP per-wave; order write->read */         \
    _Pragma("unroll") for (int kk = 0; kk < 2; ++kk) {                            \
      const int pb_ = (((kk * 2 + (g >> 1)) ^ d3) * 16 + (g & 1) * 8);            \
      bf16x8 pf1[2], pf0[2];                                                      \
      _Pragma("unroll") for (int mi = 0; mi < 2; ++mi) {                          \
        pf1[mi] = *(const bf16x8*)&sP[w][32 + mi * 16 + l15][pb_];                \
        if (ACT0) pf0[mi] = *(const bf16x8*)&sP[w][mi * 16 + l15][pb_];           \
      }                                                                           \
      _Pragma("unroll") for (int mi = 0; mi < 2; ++mi) {                          \
        lacc[1][mi] = __builtin_amdgcn_mfma_f32_16x16x32_bf16(pf1[mi], ONES, lacc[1][mi], 0, 0, 0); \
        if (ACT0)                                                                 \
          lacc[0][mi] = __builtin_amdgcn_mfma_f32_16x16x32_bf16(pf0[mi], ONES, lacc[0][mi], 0, 0, 0); \
      }                                                                           \
      _Pragma("unroll") for (int nd = 0; nd < 4; ++nd) {                          \
        bf16x8 vf = *(const bf16x8*)&sV[b_][nd * 16 + l15][((kk * 4 + g) ^ swz) * 8]; \
        _Pragma("unroll") for (int mi = 0; mi < 2; ++mi) {                        \
          oacc[1][mi][nd] = __builtin_amdgcn_mfma_f32_16x16x32_bf16(pf1[mi], vf, oacc[1][mi][nd], 0, 0, 0); \
          if (ACT0)                                                               \
            oacc[0][mi][nd] = __builtin_amdgcn_mfma_f32_16x16x32_bf16(pf0[mi], vf, oacc[0][mi][nd], 0, 0, 0); \
        }                                                                         \
      }                                                                           \
    }                                                                             \
  }

  STAGE(0, 0);
  int j = 0;
  for (; j < 2 * t0; ++j) {         // both halves, no mask
    __syncthreads();
    STAGE(j + 1, (j + 1) & 1);
    BODY(j & 1, true, false, false, 0);
  }
  {                                  // j = 2*t0: diag lower half for tile t0
    __syncthreads();
    STAGE(j + 1, (j + 1) & 1);
    BODY(j & 1, true, true, false, 0);
    ++j;
  }
  {                                  // j = 2*t0+1: diag upper half for tile t0
    __syncthreads();
    STAGE(j + 1, (j + 1) & 1);
    BODY(j & 1, true, true, false, 64);
    ++j;
  }
  for (; j < 2 * t1; ++j) {         // half1 only
    __syncthreads();
    STAGE(j + 1, (j + 1) & 1);
    BODY(j & 1, false, false, false, 0);
  }
  {                                  // j = 2*t1: diag lower half for tile t1
    __syncthreads();
    STAGE(j + 1, (j + 1) & 1);
    BODY(j & 1, false, false, true, 0);
    ++j;
  }
  {                                  // j = 2*t1+1: diag upper half (no stage)
    __syncthreads();
    BODY(j & 1, false, false, true, 64);
  }
#undef STAGE
#undef BODY

  // epilogue: lacc already in C-layout (row g*4+r) -> no shuffles
#pragma unroll
  for (int half = 0; half < 2; ++half) {
    const int tb = (half ? t1 : t0) * 128;
#pragma unroll
    for (int mi = 0; mi < 2; ++mi)
#pragma unroll
      for (int r = 0; r < 4; ++r) {
        const float inv = 1.f / lacc[half][mi][r];
        const int trow = tb + w * 32 + mi * 16 + g * 4 + r;
#pragma unroll
        for (int nd = 0; nd < 4; ++nd)
          O[(size_t)trow * DMODEL + h * 64 + nd * 16 + l15] = f2bf(oacc[half][mi][nd][r] * inv);
      }
  }
}

// ---------------------------------------------------------------------------
extern "C" void kernel_launch(void* const* d_in, const int* in_sizes, int n_in,
                              void* d_out, int out_size, void* d_ws, size_t ws_size,
                              hipStream_t stream) {
  const float* query = (const float*)d_in[0];
  const float* Wq = (const float*)d_in[1];
  const float* Wk = (const float*)d_in[2];
  const float* Wv = (const float*)d_in[3];
  const float* W1 = (const float*)d_in[4];
  const float* W2 = (const float*)d_in[5];
  float* out = (float*)d_out;

  char* ws = (char*)d_ws;
  size_t off = 0;
  auto alloc = [&](size_t bytes) { char* p = ws + off; off += (bytes + 255) & ~(size_t)255; return p; };
  // Region A (32 MB) -- all dead after attention; H aliases it.
  u16* Xb   = (u16*)alloc((size_t)4096 * 1024 * 2);
  u16* QKVb = (u16*)alloc((size_t)4096 * 1536 * 2);
  u16* Qb   = (u16*)alloc((size_t)16 * 4096 * 64 * 2);
  u16* Kb   = (u16*)alloc((size_t)4 * 4096 * 64 * 2);
  u16* Vtb  = (u16*)alloc((size_t)4 * 4096 * 64 * 2);
  u16* H    = (u16*)ws;  // [4096][4096] bf16 = 32 MB, aliases region A
  // Region B
  u16* WqkvT = (u16*)alloc((size_t)1536 * 1024 * 2);
  u16* W1T   = (u16*)alloc((size_t)4096 * 1024 * 2);
  u16* W2T   = (u16*)alloc((size_t)1024 * 4096 * 2);
  u16* AO    = (u16*)alloc((size_t)4096 * 1024 * 2);
  (void)ws_size; (void)in_sizes; (void)n_in; (void)out_size;

  f2b_copy<<<4096, 256, 0, stream>>>(query, Xb, 4096 * 1024);
  wtrans<<<dim3(16, 16), 256, 0, stream>>>(Wq, WqkvT, 1024, 1024);
  wtrans<<<dim3(4, 16), 256, 0, stream>>>(Wk, WqkvT + (size_t)1024 * 1024, 1024, 256);
  wtrans<<<dim3(4, 16), 256, 0, stream>>>(Wv, WqkvT + (size_t)1280 * 1024, 1024, 256);
  wtrans<<<dim3(64, 16), 256, 0, stream>>>(W1, W1T, 1024, 4096);
  wtrans<<<dim3(16, 64), 256, 0, stream>>>(W2, W2T, 4096, 1024);

  gemm_bt<2, 0, u16><<<dim3(12, 64), 256, 0, stream>>>(Xb, WqkvT, QKVb, 4096, 1536, 1024);
  rope_qk<<<4096, 256, 0, stream>>>(QKVb, Qb, Kb);
  vtrans<<<dim3(64, 4), 256, 0, stream>>>(QKVb, Vtb);
  attn<<<dim3(16, 16), 256, 0, stream>>>(Qb, Kb, Vtb, AO);
  gemm_bt<4, 1, u16><<<dim3(32, 32), 256, 0, stream>>>(AO, W1T, H, 4096, 4096, 1024);
  gemm_bt<2, 0, float><<<dim3(8, 64), 256, 0, stream>>>(H, W2T, out, 4096, 1024, 4096);
}

// Round 5
// 317.963 us; speedup vs baseline: 1.0834x; 1.0834x over previous
//
#include <hip/hip_runtime.h>
#include <stdint.h>

typedef unsigned short u16;
typedef __bf16 bf16x8 __attribute__((ext_vector_type(8)));
typedef float f32x4 __attribute__((ext_vector_type(4)));

#define T_SEQ 4096
#define DMODEL 1024

__device__ __forceinline__ float bf2f(u16 x) {
  union { uint32_t u; float f; } v; v.u = ((uint32_t)x) << 16; return v.f;
}
__device__ __forceinline__ u16 f2bf(float f) {
  union { float f; uint32_t u; } v; v.f = f;
  return (u16)((v.u + 0x7FFFu + ((v.u >> 16) & 1u)) >> 16);  // RNE, finite inputs only
}
__device__ __forceinline__ float fexp2(float x) {
#if __has_builtin(__builtin_amdgcn_exp2f)
  return __builtin_amdgcn_exp2f(x);
#else
  return __expf(x * 0.6931471805599453f);
#endif
}
// pack two f32 -> packed bf16x2 (lo in low16)
__device__ __forceinline__ uint32_t pack_bf16(float lo, float hi) {
#if __has_builtin(__builtin_amdgcn_cvt_pk_bf16_f32)
  typedef __bf16 bf16x2_t __attribute__((ext_vector_type(2)));
  union { bf16x2_t v; uint32_t u; } c;
  c.v = __builtin_amdgcn_cvt_pk_bf16_f32(lo, hi);
  return c.u;
#else
  union { float f; uint32_t u; } a, b;
  a.f = lo; b.f = hi;
  return __builtin_amdgcn_perm(b.u + 0x8000u, a.u + 0x8000u, 0x07060302u);
#endif
}
// async global->LDS, 16B/lane. LDS dest = wave-uniform base + lane*16 (guide §5 caveat).
__device__ __forceinline__ void async16(void* lds, const void* g) {
  __builtin_amdgcn_global_load_lds(
      (__attribute__((address_space(1))) void*)const_cast<void*>(g),
      (__attribute__((address_space(3))) void*)lds, 16, 0, 0);
}
__device__ __forceinline__ void storeC(u16* C, size_t i, float v) { C[i] = f2bf(v); }
__device__ __forceinline__ void storeC(float* C, size_t i, float v) { C[i] = v; }

// ---------------- fp32 -> bf16 elementwise copy ----------------
__global__ void __launch_bounds__(256) f2b_copy(const float* __restrict__ in,
                                                u16* __restrict__ out, int n) {
  int idx = (blockIdx.x * 256 + threadIdx.x) * 4;
  if (idx >= n) return;
  float4 v = *(const float4*)(in + idx);
  union { u16 s[4]; uint2 q; } b;
  b.s[0] = f2bf(v.x); b.s[1] = f2bf(v.y); b.s[2] = f2bf(v.z); b.s[3] = f2bf(v.w);
  *(uint2*)(out + idx) = b.q;
}

// ---------------- fp32 [K][N] -> bf16 [N][K] tiled transpose ----------------
__global__ void __launch_bounds__(256) wtrans(const float* __restrict__ in,
                                              u16* __restrict__ out, int K, int N) {
  __shared__ float tile[64][65];
  const int n0 = blockIdx.x * 64, k0 = blockIdx.y * 64;
  const int tid = threadIdx.x;
  const int r = tid >> 2, c = (tid & 3) * 16;
#pragma unroll
  for (int j = 0; j < 4; ++j) {
    float4 v = *(const float4*)&in[(size_t)(k0 + r) * N + n0 + c + j * 4];
    tile[r][c + j * 4 + 0] = v.x; tile[r][c + j * 4 + 1] = v.y;
    tile[r][c + j * 4 + 2] = v.z; tile[r][c + j * 4 + 3] = v.w;
  }
  __syncthreads();
  union { u16 s[16]; uint4 q[2]; } buf;
#pragma unroll
  for (int j = 0; j < 16; ++j) buf.s[j] = f2bf(tile[c + j][r]);
  u16* dst = out + (size_t)(n0 + r) * K + k0 + c;
  *(uint4*)(dst) = buf.q[0];
  *(uint4*)(dst + 8) = buf.q[1];
}

// ---------------- bf16 V slice transpose: QKV[t][1280+h*64+d] -> Vt[h][d][t] ----------------
__global__ void __launch_bounds__(256) vtrans(const u16* __restrict__ qkv,
                                              u16* __restrict__ Vt) {
  __shared__ u16 tile[64][65];
  const int t0 = blockIdx.x * 64, h = blockIdx.y;
  const int tid = threadIdx.x;
  const int r = tid >> 2, q4 = (tid & 3) * 16;
  const u16* src = qkv + (size_t)(t0 + r) * 1536 + 1280 + h * 64 + q4;
  union { u16 s[16]; uint4 q[2]; } buf;
  buf.q[0] = *(const uint4*)(src);
  buf.q[1] = *(const uint4*)(src + 8);
#pragma unroll
  for (int j = 0; j < 16; ++j) tile[r][q4 + j] = buf.s[j];
  __syncthreads();
#pragma unroll
  for (int j = 0; j < 16; ++j) buf.s[j] = tile[q4 + j][r];
  u16* dst = Vt + ((size_t)h * 64 + r) * T_SEQ + t0 + q4;
  *(uint4*)(dst) = buf.q[0];
  *(uint4*)(dst + 8) = buf.q[1];
}

// ---------------- RoPE: QKV[t][1536] -> Q[16][T][64] (x 0.125*log2e folded), K[4][T][64] ----
__global__ void __launch_bounds__(256) rope_qk(const u16* __restrict__ qkv,
                                               u16* __restrict__ Q, u16* __restrict__ Ko) {
  const int t = blockIdx.x;
  const int tid = threadIdx.x;
  const int i = tid & 31;
  const float ang = (float)t * powf(10000.f, -(float)i * (1.f / 32.f));
  float s, c;
  sincosf(ang, &s, &c);
  const u16* row = qkv + (size_t)t * 1536;
  const float QS = 0.125f * 1.4426950408889634f;
  const float cq = c * QS, sq = s * QS;
#pragma unroll
  for (int it = 0; it < 2; ++it) {
    int h = (tid >> 5) + it * 8;
    float x1 = bf2f(row[h * 64 + i]);
    float x2 = bf2f(row[h * 64 + 32 + i]);
    size_t o = ((size_t)h * T_SEQ + t) * 64 + i;
    Q[o] = f2bf(x1 * cq - x2 * sq);
    Q[o + 32] = f2bf(x2 * cq + x1 * sq);
  }
  if (tid < 128) {
    int h = tid >> 5;
    float x1 = bf2f(row[1024 + h * 64 + i]);
    float x2 = bf2f(row[1024 + h * 64 + 32 + i]);
    size_t o = ((size_t)h * T_SEQ + t) * 64 + i;
    Ko[o] = f2bf(x1 * c - x2 * s);
    Ko[o + 32] = f2bf(x2 * c + x1 * s);
  }
}

// ---------------- bf16 GEMM: C[M][N] = A[M][K] @ Bt[N][K]^T ----------------
template <int AM, int ACT, typename OutT>
__global__ void __launch_bounds__(256) gemm_bt(const u16* __restrict__ A,
                                               const u16* __restrict__ Bt,
                                               OutT* __restrict__ C,
                                               int M, int N, int K) {
  __shared__ u16 sA[AM * 32][64];
  __shared__ u16 sB[128][64];
  const int tid = threadIdx.x;
  const int w = tid >> 6, lane = tid & 63;
  const int g = lane >> 4, l15 = lane & 15;
  const int r8 = lane >> 3, c8 = lane & 7;
  const int bm = blockIdx.y * (AM * 32), bn = blockIdx.x * 128;

  f32x4 acc[AM][4];
#pragma unroll
  for (int i = 0; i < AM; ++i)
#pragma unroll
    for (int j = 0; j < 4; ++j) acc[i][j] = (f32x4){0.f, 0.f, 0.f, 0.f};

  const u16* Ag = A + (size_t)(bm + w * (AM * 8) + r8) * K + (c8 ^ r8) * 8;
  const u16* Bg = Bt + (size_t)(bn + w * 32 + r8) * K + (c8 ^ r8) * 8;
  const int mrow = (w >> 1) * (AM * 16), ncol = (w & 1) * 64;
  const int swz = l15 & 7;

  for (int k0 = 0; k0 < K; k0 += 64) {
#pragma unroll
    for (int t = 0; t < AM; ++t)
      async16(&sA[w * (AM * 8) + t * 8][0], Ag + (size_t)(t * 8) * K + k0);
#pragma unroll
    for (int t = 0; t < 4; ++t)
      async16(&sB[w * 32 + t * 8][0], Bg + (size_t)(t * 8) * K + k0);
    __syncthreads();
#pragma unroll
    for (int kk = 0; kk < 2; ++kk) {
      const int cb = ((kk * 4 + g) ^ swz) * 8;
      bf16x8 a[AM], b[4];
#pragma unroll
      for (int i = 0; i < AM; ++i) a[i] = *(const bf16x8*)&sA[mrow + i * 16 + l15][cb];
#pragma unroll
      for (int i = 0; i < 4; ++i) b[i] = *(const bf16x8*)&sB[ncol + i * 16 + l15][cb];
#pragma unroll
      for (int mi = 0; mi < AM; ++mi)
#pragma unroll
        for (int ni = 0; ni < 4; ++ni)
          acc[mi][ni] = __builtin_amdgcn_mfma_f32_16x16x32_bf16(a[mi], b[ni], acc[mi][ni], 0, 0, 0);
    }
    __syncthreads();
  }
#pragma unroll
  for (int mi = 0; mi < AM; ++mi)
#pragma unroll
    for (int ni = 0; ni < 4; ++ni)
#pragma unroll
      for (int r = 0; r < 4; ++r) {
        int row = bm + mrow + mi * 16 + g * 4 + r;
        int col = bn + ncol + ni * 16 + l15;
        float v = acc[mi][ni][r];
        if (ACT == 1) v = v / (1.f + __expf(-v));  // SiLU
        storeC(C, (size_t)row * N + col, v);
      }
}

// ---------------- Flash attention (causal, GQA 16q/4kv, D=64) ----------------
// 128-row q-tile pairs (t0=pr, t1=31-pr) x kv-parity split (split s takes kv
// tiles j == s mod 2): grid 32x16 = 512 blocks, ALL with exactly 33 BODYs,
// 2 blocks/CU -> 2 waves/SIMD (r4's 1-wave/SIMD latency exposure fixed).
// No-max softmax makes partials addable: each split writes unnormalized
// partial O (bf16) + partial row-sum l (f32); attn_combine merges.
// S^T via mfma(kf,qf); P round-trips per-wave LDS [64][68] (pad +4,
// write/read both at the 4-access/bank minimum). Row sums via ones-MFMA.
__global__ void __launch_bounds__(256, 2) attn(const u16* __restrict__ Q,
                                               const u16* __restrict__ K,
                                               const u16* __restrict__ Vt,
                                               u16* __restrict__ O0,
                                               u16* __restrict__ O1,
                                               float* __restrict__ L0,
                                               float* __restrict__ L1) {
  __shared__ u16 sK[2][64][64];
  __shared__ u16 sV[2][64][64];     // sV[b][d][kv]
  __shared__ u16 sP[4][64][68];     // [wave][half*32+mi*16+q16][kv] pad+4
  const int pr = blockIdx.x >> 1;
  const int split = blockIdx.x & 1;
  const int h = blockIdx.y;
  const int kvh = h >> 2;
  const int tid = threadIdx.x;
  const int w = tid >> 6, lane = tid & 63;
  const int g = lane >> 4, l15 = lane & 15;
  const int r8 = lane >> 3, c8 = lane & 7;
  const int swz = l15 & 7;
  const int t0 = pr, t1 = 31 - pr;
  const int off = split * 64;

  u16* Op = split ? O1 : O0;
  float* Lp = split ? L1 : L0;

  // Q fragments straight from global (B-operand: n=q=l15, k=d)
  bf16x8 qf[2][2][2];
  {
    const u16* Qh = Q + (size_t)h * T_SEQ * 64;
#pragma unroll
    for (int half = 0; half < 2; ++half)
#pragma unroll
      for (int mi = 0; mi < 2; ++mi) {
        const int q = (half ? t1 : t0) * 128 + w * 32 + mi * 16 + l15;
#pragma unroll
        for (int kk = 0; kk < 2; ++kk)
          qf[half][mi][kk] = *(const bf16x8*)(Qh + (size_t)q * 64 + (kk * 4 + g) * 8);
      }
  }

  f32x4 oacc[2][2][4];
  f32x4 lacc[2][2];
#pragma unroll
  for (int half = 0; half < 2; ++half)
#pragma unroll
    for (int mi = 0; mi < 2; ++mi) {
      lacc[half][mi] = (f32x4){0.f, 0.f, 0.f, 0.f};
#pragma unroll
      for (int nd = 0; nd < 4; ++nd) oacc[half][mi][nd] = (f32x4){0.f, 0.f, 0.f, 0.f};
    }

  bf16x8 ONES;
  {
    union { u16 s[8]; bf16x8 v; } o;
#pragma unroll
    for (int i = 0; i < 8; ++i) o.s[i] = 0x3F80;  // bf16 1.0
    ONES = o.v;
  }

  const u16* Kg = K + ((size_t)kvh * T_SEQ + w * 16 + r8) * 64 + (c8 ^ r8) * 8;
  const u16* Vg = Vt + ((size_t)kvh * 64 + w * 16 + r8) * T_SEQ + (c8 ^ r8) * 8;

#define STAGE(J, B)                                                     \
  {                                                                     \
    const int kv0_ = (J) * 64;                                          \
    async16(&sK[B][w * 16 + 0][0], Kg + (size_t)kv0_ * 64);             \
    async16(&sK[B][w * 16 + 8][0], Kg + (size_t)(kv0_ + 8) * 64);       \
    async16(&sV[B][w * 16 + 0][0], Vg + kv0_);                          \
    async16(&sV[B][w * 16 + 8][0], Vg + (size_t)8 * T_SEQ + kv0_);      \
  }

#define BODY(B, ACT0, M0, M1)                                                     \
  {                                                                               \
    const int b_ = (B);                                                           \
    f32x4 s1[2][4], s0[2][4];                                                     \
    _Pragma("unroll") for (int mi = 0; mi < 2; ++mi)                              \
    _Pragma("unroll") for (int kt = 0; kt < 4; ++kt) {                            \
      s1[mi][kt] = (f32x4){0.f, 0.f, 0.f, 0.f};                                   \
      if (ACT0) s0[mi][kt] = (f32x4){0.f, 0.f, 0.f, 0.f};                         \
    }                                                                             \
    _Pragma("unroll") for (int kt = 0; kt < 4; ++kt)                              \
    _Pragma("unroll") for (int kk = 0; kk < 2; ++kk) {                            \
      bf16x8 kf = *(const bf16x8*)&sK[b_][kt * 16 + l15][((kk * 4 + g) ^ swz) * 8]; \
      _Pragma("unroll") for (int mi = 0; mi < 2; ++mi) {                          \
        s1[mi][kt] = __builtin_amdgcn_mfma_f32_16x16x32_bf16(kf, qf[1][mi][kk], s1[mi][kt], 0, 0, 0); \
        if (ACT0)                                                                 \
          s0[mi][kt] = __builtin_amdgcn_mfma_f32_16x16x32_bf16(kf, qf[0][mi][kk], s0[mi][kt], 0, 0, 0); \
      }                                                                           \
    }                                                                             \
    _Pragma("unroll") for (int mi = 0; mi < 2; ++mi) {                            \
      const int thr_ = w * 32 + mi * 16 + l15 - off;                              \
      _Pragma("unroll") for (int kt = 0; kt < 4; ++kt) {                          \
        float p_[4];                                                              \
        _Pragma("unroll") for (int r = 0; r < 4; ++r) {                           \
          float p = fexp2(s1[mi][kt][r]);                                         \
          if (M1 && (kt * 16 + g * 4 + r > thr_)) p = 0.f;                        \
          p_[r] = p;                                                              \
        }                                                                         \
        uint2 pk;                                                                 \
        pk.x = pack_bf16(p_[0], p_[1]);                                           \
        pk.y = pack_bf16(p_[2], p_[3]);                                           \
        *(uint2*)&sP[w][32 + mi * 16 + l15][kt * 16 + g * 4] = pk;                \
      }                                                                           \
      if (ACT0) {                                                                 \
        _Pragma("unroll") for (int kt = 0; kt < 4; ++kt) {                        \
          float p_[4];                                                            \
          _Pragma("unroll") for (int r = 0; r < 4; ++r) {                         \
            float p = fexp2(s0[mi][kt][r]);                                       \
            if (M0 && (kt * 16 + g * 4 + r > thr_)) p = 0.f;                      \
            p_[r] = p;                                                            \
          }                                                                       \
          uint2 pk;                                                               \
          pk.x = pack_bf16(p_[0], p_[1]);                                         \
          pk.y = pack_bf16(p_[2], p_[3]);                                         \
          *(uint2*)&sP[w][mi * 16 + l15][kt * 16 + g * 4] = pk;                   \
        }                                                                         \
      }                                                                           \
    }                                                                             \
    __builtin_amdgcn_wave_barrier(); /* sP per-wave; order write->read */         \
    _Pragma("unroll") for (int kk = 0; kk < 2; ++kk) {                            \
      bf16x8 pf1[2], pf0[2];                                                      \
      _Pragma("unroll") for (int mi = 0; mi < 2; ++mi) {                          \
        pf1[mi] = *(const bf16x8*)&sP[w][32 + mi * 16 + l15][kk * 32 + g * 8];    \
        if (ACT0) pf0[mi] = *(const bf16x8*)&sP[w][mi * 16 + l15][kk * 32 + g * 8]; \
      }                                                                           \
      _Pragma("unroll") for (int mi = 0; mi < 2; ++mi) {                          \
        lacc[1][mi] = __builtin_amdgcn_mfma_f32_16x16x32_bf16(pf1[mi], ONES, lacc[1][mi], 0, 0, 0); \
        if (ACT0)                                                                 \
          lacc[0][mi] = __builtin_amdgcn_mfma_f32_16x16x32_bf16(pf0[mi], ONES, lacc[0][mi], 0, 0, 0); \
      }                                                                           \
      _Pragma("unroll") for (int nd = 0; nd < 4; ++nd) {                          \
        bf16x8 vf = *(const bf16x8*)&sV[b_][nd * 16 + l15][((kk * 4 + g) ^ swz) * 8]; \
        _Pragma("unroll") for (int mi = 0; mi < 2; ++mi) {                        \
          oacc[1][mi][nd] = __builtin_amdgcn_mfma_f32_16x16x32_bf16(pf1[mi], vf, oacc[1][mi][nd], 0, 0, 0); \
          if (ACT0)                                                               \
            oacc[0][mi][nd] = __builtin_amdgcn_mfma_f32_16x16x32_bf16(pf0[mi], vf, oacc[0][mi][nd], 0, 0, 0); \
        }                                                                         \
      }                                                                           \
    }                                                                             \
  }

  // kv tiles j == split (mod 2); diag for tile t at j = 2t+split (thr off=64*split)
  const int e0 = 2 * t0 + split, e1 = 2 * t1 + split;
  STAGE(split, 0);
  int jj = split, b = 0;
  for (; jj < e0; jj += 2, b ^= 1) {   // both halves, no mask
    __syncthreads();
    STAGE(jj + 2, b ^ 1);
    BODY(b, true, false, false);
  }
  {                                     // jj == e0: dual, mask half0
    __syncthreads();
    STAGE(jj + 2, b ^ 1);               // e0+2 <= e1 always (t1 >= t0+1)
    BODY(b, true, true, false);
    jj += 2; b ^= 1;
  }
  for (; jj < e1; jj += 2, b ^= 1) {   // half1 only
    __syncthreads();
    STAGE(jj + 2, b ^ 1);
    BODY(b, false, false, false);
  }
  {                                     // jj == e1: half1, mask
    __syncthreads();
    BODY(b, false, false, true);
  }
#undef STAGE
#undef BODY

  // epilogue: write UNNORMALIZED partial O (bf16) + partial l (f32)
#pragma unroll
  for (int half = 0; half < 2; ++half) {
    const int tb = (half ? t1 : t0) * 128;
#pragma unroll
    for (int mi = 0; mi < 2; ++mi)
#pragma unroll
      for (int r = 0; r < 4; ++r) {
        const int trow = tb + w * 32 + mi * 16 + g * 4 + r;
#pragma unroll
        for (int nd = 0; nd < 4; ++nd)
          Op[(size_t)trow * DMODEL + h * 64 + nd * 16 + l15] = f2bf(oacc[half][mi][nd][r]);
        if (l15 == 0) Lp[h * T_SEQ + trow] = lacc[half][mi][r];
      }
  }
}

// ---------------- combine partials: AO = (O0+O1)/(l0+l1) ----------------
__global__ void __launch_bounds__(256) attn_combine(const u16* __restrict__ O0,
                                                    const u16* __restrict__ O1,
                                                    const float* __restrict__ L0,
                                                    const float* __restrict__ L1,
                                                    u16* __restrict__ AO) {
  const int t = blockIdx.x, tid = threadIdx.x;
  const int h = tid >> 4, d4 = (tid & 15) * 4;
  const float inv = 1.f / (L0[h * T_SEQ + t] + L1[h * T_SEQ + t]);
  const size_t idx = (size_t)t * DMODEL + h * 64 + d4;
  union { uint2 q; u16 s[4]; } a, b, o;
  a.q = *(const uint2*)(O0 + idx);
  b.q = *(const uint2*)(O1 + idx);
#pragma unroll
  for (int i = 0; i < 4; ++i) o.s[i] = f2bf((bf2f(a.s[i]) + bf2f(b.s[i])) * inv);
  *(uint2*)(AO + idx) = o.q;
}

// ---------------------------------------------------------------------------
extern "C" void kernel_launch(void* const* d_in, const int* in_sizes, int n_in,
                              void* d_out, int out_size, void* d_ws, size_t ws_size,
                              hipStream_t stream) {
  const float* query = (const float*)d_in[0];
  const float* Wq = (const float*)d_in[1];
  const float* Wk = (const float*)d_in[2];
  const float* Wv = (const float*)d_in[3];
  const float* W1 = (const float*)d_in[4];
  const float* W2 = (const float*)d_in[5];
  float* out = (float*)d_out;

  char* ws = (char*)d_ws;
  size_t off = 0;
  auto alloc = [&](size_t bytes) { char* p = ws + off; off += (bytes + 255) & ~(size_t)255; return p; };
  // Region A (32 MB) -- all dead after attention; H aliases it.
  u16* Xb   = (u16*)alloc((size_t)4096 * 1024 * 2);
  u16* QKVb = (u16*)alloc((size_t)4096 * 1536 * 2);
  u16* Qb   = (u16*)alloc((size_t)16 * 4096 * 64 * 2);
  u16* Kb   = (u16*)alloc((size_t)4 * 4096 * 64 * 2);
  u16* Vtb  = (u16*)alloc((size_t)4 * 4096 * 64 * 2);
  u16* H    = (u16*)ws;  // [4096][4096] bf16 = 32 MB, aliases region A
  // Attention partials alias Xb / QKVb (dead by the time attn runs):
  u16*   O0p = Xb;                               // 8 MB
  u16*   O1p = QKVb;                             // 8 MB (first 4M u16 of QKVb)
  float* L0p = (float*)(QKVb + (size_t)4096 * 1024);  // 256 KB
  float* L1p = L0p + 16 * T_SEQ;                      // 256 KB
  // Region B
  u16* WqkvT = (u16*)alloc((size_t)1536 * 1024 * 2);
  u16* W1T   = (u16*)alloc((size_t)4096 * 1024 * 2);
  u16* W2T   = (u16*)alloc((size_t)1024 * 4096 * 2);
  u16* AO    = (u16*)alloc((size_t)4096 * 1024 * 2);
  (void)ws_size; (void)in_sizes; (void)n_in; (void)out_size;

  f2b_copy<<<4096, 256, 0, stream>>>(query, Xb, 4096 * 1024);
  wtrans<<<dim3(16, 16), 256, 0, stream>>>(Wq, WqkvT, 1024, 1024);
  wtrans<<<dim3(4, 16), 256, 0, stream>>>(Wk, WqkvT + (size_t)1024 * 1024, 1024, 256);
  wtrans<<<dim3(4, 16), 256, 0, stream>>>(Wv, WqkvT + (size_t)1280 * 1024, 1024, 256);
  wtrans<<<dim3(64, 16), 256, 0, stream>>>(W1, W1T, 1024, 4096);
  wtrans<<<dim3(16, 64), 256, 0, stream>>>(W2, W2T, 4096, 1024);

  gemm_bt<2, 0, u16><<<dim3(12, 64), 256, 0, stream>>>(Xb, WqkvT, QKVb, 4096, 1536, 1024);
  rope_qk<<<4096, 256, 0, stream>>>(QKVb, Qb, Kb);
  vtrans<<<dim3(64, 4), 256, 0, stream>>>(QKVb, Vtb);
  attn<<<dim3(32, 16), 256, 0, stream>>>(Qb, Kb, Vtb, O0p, O1p, L0p, L1p);
  attn_combine<<<4096, 256, 0, stream>>>(O0p, O1p, L0p, L1p, AO);
  gemm_bt<4, 1, u16><<<dim3(32, 32), 256, 0, stream>>>(AO, W1T, H, 4096, 4096, 1024);
  gemm_bt<2, 0, float><<<dim3(8, 64), 256, 0, stream>>>(H, W2T, out, 4096, 1024, 4096);
}

// Round 6
// 291.739 us; speedup vs baseline: 1.1808x; 1.0899x over previous
//
#include <hip/hip_runtime.h>
#include <stdint.h>

typedef unsigned short u16;
typedef __bf16 bf16x8 __attribute__((ext_vector_type(8)));
typedef float f32x4 __attribute__((ext_vector_type(4)));

#define T_SEQ 4096
#define DMODEL 1024

__device__ __forceinline__ float bf2f(u16 x) {
  union { uint32_t u; float f; } v; v.u = ((uint32_t)x) << 16; return v.f;
}
__device__ __forceinline__ u16 f2bf(float f) {
  union { float f; uint32_t u; } v; v.f = f;
  return (u16)((v.u + 0x7FFFu + ((v.u >> 16) & 1u)) >> 16);  // RNE, finite inputs only
}
__device__ __forceinline__ float fexp2(float x) {
#if __has_builtin(__builtin_amdgcn_exp2f)
  return __builtin_amdgcn_exp2f(x);
#else
  return __expf(x * 0.6931471805599453f);
#endif
}
// pack two f32 -> packed bf16x2 (lo in low16)
__device__ __forceinline__ uint32_t pack_bf16(float lo, float hi) {
#if __has_builtin(__builtin_amdgcn_cvt_pk_bf16_f32)
  typedef __bf16 bf16x2_t __attribute__((ext_vector_type(2)));
  union { bf16x2_t v; uint32_t u; } c;
  c.v = __builtin_amdgcn_cvt_pk_bf16_f32(lo, hi);
  return c.u;
#else
  union { float f; uint32_t u; } a, b;
  a.f = lo; b.f = hi;
  return __builtin_amdgcn_perm(b.u + 0x8000u, a.u + 0x8000u, 0x07060302u);
#endif
}
// async global->LDS, 16B/lane. LDS dest = wave-uniform base + lane*16 (guide §5 caveat).
__device__ __forceinline__ void async16(void* lds, const void* g) {
  __builtin_amdgcn_global_load_lds(
      (__attribute__((address_space(1))) void*)const_cast<void*>(g),
      (__attribute__((address_space(3))) void*)lds, 16, 0, 0);
}
__device__ __forceinline__ void storeC(u16* C, size_t i, float v) { C[i] = f2bf(v); }
__device__ __forceinline__ void storeC(float* C, size_t i, float v) { C[i] = v; }

// ---------------- fused prep: fp32->bf16 copy of X + all 5 weight transposes ----
// fp32 [K][N] -> bf16 [N][K]; block-range dispatch, all shapes compile-time.
__device__ __forceinline__ void wtrans_body(const float* __restrict__ in,
                                            u16* __restrict__ out, int K, int N,
                                            int bx, int by, int tid,
                                            float (*tile)[65]) {
  const int n0 = bx * 64, k0 = by * 64;
  const int r = tid >> 2, c = (tid & 3) * 16;
#pragma unroll
  for (int j = 0; j < 4; ++j) {
    float4 v = *(const float4*)&in[(size_t)(k0 + r) * N + n0 + c + j * 4];
    tile[r][c + j * 4 + 0] = v.x; tile[r][c + j * 4 + 1] = v.y;
    tile[r][c + j * 4 + 2] = v.z; tile[r][c + j * 4 + 3] = v.w;
  }
  __syncthreads();
  union { u16 s[16]; uint4 q[2]; } buf;
#pragma unroll
  for (int j = 0; j < 16; ++j) buf.s[j] = f2bf(tile[c + j][r]);
  u16* dst = out + (size_t)(n0 + r) * K + k0 + c;
  *(uint4*)(dst) = buf.q[0];
  *(uint4*)(dst + 8) = buf.q[1];
}

__global__ void __launch_bounds__(256) prep(const float* __restrict__ query,
                                            const float* __restrict__ Wq,
                                            const float* __restrict__ Wk,
                                            const float* __restrict__ Wv,
                                            const float* __restrict__ W1,
                                            const float* __restrict__ W2,
                                            u16* __restrict__ Xb,
                                            u16* __restrict__ WqkvT,
                                            u16* __restrict__ W1T,
                                            u16* __restrict__ W2T) {
  __shared__ float tile[64][65];
  const int b = blockIdx.x, tid = threadIdx.x;
  if (b < 4096) {                       // f2b copy: query -> Xb (4M elems, 4/thread)
    int idx = (b * 256 + tid) * 4;
    float4 v = *(const float4*)(query + idx);
    union { u16 s[4]; uint2 q; } o;
    o.s[0] = f2bf(v.x); o.s[1] = f2bf(v.y); o.s[2] = f2bf(v.z); o.s[3] = f2bf(v.w);
    *(uint2*)(Xb + idx) = o.q;
  } else if (b < 4352) {                // Wq [1024][1024]
    int t = b - 4096;
    wtrans_body(Wq, WqkvT, 1024, 1024, t & 15, t >> 4, tid, tile);
  } else if (b < 4416) {                // Wk [1024][256]
    int t = b - 4352;
    wtrans_body(Wk, WqkvT + (size_t)1024 * 1024, 1024, 256, t & 3, t >> 2, tid, tile);
  } else if (b < 4480) {                // Wv [1024][256]
    int t = b - 4416;
    wtrans_body(Wv, WqkvT + (size_t)1280 * 1024, 1024, 256, t & 3, t >> 2, tid, tile);
  } else if (b < 5504) {                // W1 [1024][4096]
    int t = b - 4480;
    wtrans_body(W1, W1T, 1024, 4096, t & 63, t >> 6, tid, tile);
  } else {                              // W2 [4096][1024]
    int t = b - 5504;
    wtrans_body(W2, W2T, 4096, 1024, t & 15, t >> 4, tid, tile);
  }
}

// ---------------- fused RoPE + V transpose ----------------
// blocks [0,4096): RoPE row t; blocks [4096,4352): V-slice transpose.
__global__ void __launch_bounds__(256) rope_vt(const u16* __restrict__ qkv,
                                               u16* __restrict__ Q,
                                               u16* __restrict__ Ko,
                                               u16* __restrict__ Vt) {
  __shared__ u16 tile[64][65];
  const int b = blockIdx.x, tid = threadIdx.x;
  if (b < 4096) {
    const int t = b;
    const int i = tid & 31;
    const float ang = (float)t * powf(10000.f, -(float)i * (1.f / 32.f));
    float s, c;
    sincosf(ang, &s, &c);
    const u16* row = qkv + (size_t)t * 1536;
    const float QS = 0.125f * 1.4426950408889634f;  // attn scale * log2(e)
    const float cq = c * QS, sq = s * QS;
#pragma unroll
    for (int it = 0; it < 2; ++it) {
      int h = (tid >> 5) + it * 8;
      float x1 = bf2f(row[h * 64 + i]);
      float x2 = bf2f(row[h * 64 + 32 + i]);
      size_t o = ((size_t)h * T_SEQ + t) * 64 + i;
      Q[o] = f2bf(x1 * cq - x2 * sq);
      Q[o + 32] = f2bf(x2 * cq + x1 * sq);
    }
    if (tid < 128) {
      int h = tid >> 5;
      float x1 = bf2f(row[1024 + h * 64 + i]);
      float x2 = bf2f(row[1024 + h * 64 + 32 + i]);
      size_t o = ((size_t)h * T_SEQ + t) * 64 + i;
      Ko[o] = f2bf(x1 * c - x2 * s);
      Ko[o + 32] = f2bf(x2 * c + x1 * s);
    }
  } else {
    const int t = b - 4096;
    const int t0 = (t & 63) * 64, h = t >> 6;
    const int r = tid >> 2, q4 = (tid & 3) * 16;
    const u16* src = qkv + (size_t)(t0 + r) * 1536 + 1280 + h * 64 + q4;
    union { u16 s[16]; uint4 q[2]; } buf;
    buf.q[0] = *(const uint4*)(src);
    buf.q[1] = *(const uint4*)(src + 8);
#pragma unroll
    for (int j = 0; j < 16; ++j) tile[r][q4 + j] = buf.s[j];
    __syncthreads();
#pragma unroll
    for (int j = 0; j < 16; ++j) buf.s[j] = tile[q4 + j][r];
    u16* dst = Vt + ((size_t)h * 64 + r) * T_SEQ + t0 + q4;
    *(uint4*)(dst) = buf.q[0];
    *(uint4*)(dst + 8) = buf.q[1];
  }
}

// ---------------- bf16 GEMM: C[M][N] = A[M][K] @ Bt[N][K]^T ----------------
template <int AM, int ACT, typename OutT>
__global__ void __launch_bounds__(256) gemm_bt(const u16* __restrict__ A,
                                               const u16* __restrict__ Bt,
                                               OutT* __restrict__ C,
                                               int M, int N, int K) {
  __shared__ u16 sA[AM * 32][64];
  __shared__ u16 sB[128][64];
  const int tid = threadIdx.x;
  const int w = tid >> 6, lane = tid & 63;
  const int g = lane >> 4, l15 = lane & 15;
  const int r8 = lane >> 3, c8 = lane & 7;
  const int bm = blockIdx.y * (AM * 32), bn = blockIdx.x * 128;

  f32x4 acc[AM][4];
#pragma unroll
  for (int i = 0; i < AM; ++i)
#pragma unroll
    for (int j = 0; j < 4; ++j) acc[i][j] = (f32x4){0.f, 0.f, 0.f, 0.f};

  const u16* Ag = A + (size_t)(bm + w * (AM * 8) + r8) * K + (c8 ^ r8) * 8;
  const u16* Bg = Bt + (size_t)(bn + w * 32 + r8) * K + (c8 ^ r8) * 8;
  const int mrow = (w >> 1) * (AM * 16), ncol = (w & 1) * 64;
  const int swz = l15 & 7;

  for (int k0 = 0; k0 < K; k0 += 64) {
#pragma unroll
    for (int t = 0; t < AM; ++t)
      async16(&sA[w * (AM * 8) + t * 8][0], Ag + (size_t)(t * 8) * K + k0);
#pragma unroll
    for (int t = 0; t < 4; ++t)
      async16(&sB[w * 32 + t * 8][0], Bg + (size_t)(t * 8) * K + k0);
    __syncthreads();
#pragma unroll
    for (int kk = 0; kk < 2; ++kk) {
      const int cb = ((kk * 4 + g) ^ swz) * 8;
      bf16x8 a[AM], b[4];
#pragma unroll
      for (int i = 0; i < AM; ++i) a[i] = *(const bf16x8*)&sA[mrow + i * 16 + l15][cb];
#pragma unroll
      for (int i = 0; i < 4; ++i) b[i] = *(const bf16x8*)&sB[ncol + i * 16 + l15][cb];
#pragma unroll
      for (int mi = 0; mi < AM; ++mi)
#pragma unroll
        for (int ni = 0; ni < 4; ++ni)
          acc[mi][ni] = __builtin_amdgcn_mfma_f32_16x16x32_bf16(a[mi], b[ni], acc[mi][ni], 0, 0, 0);
    }
    __syncthreads();
  }
#pragma unroll
  for (int mi = 0; mi < AM; ++mi)
#pragma unroll
    for (int ni = 0; ni < 4; ++ni)
#pragma unroll
      for (int r = 0; r < 4; ++r) {
        int row = bm + mrow + mi * 16 + g * 4 + r;
        int col = bn + ncol + ni * 16 + l15;
        float v = acc[mi][ni][r];
        if (ACT == 1) v = v / (1.f + __expf(-v));  // SiLU
        storeC(C, (size_t)row * N + col, v);
      }
}

// ---------------- W2 GEMM, AM=4 + split-K x2 ----------------
// out[4096][1024] (fp32) = H[4096][4096] @ W2T[1024][4096]^T.
// z=0 covers k<2048 -> fp32 partial straight into out; z=1 covers k>=2048 ->
// bf16 partial into P1 (aliases dead W1T). w2_combine: out += bf16(P1).
// AM=4 shape is MFMA-bound (4:1 MFMA:ds_read vs AM=2's 2.7:1 LDS-bound);
// split-K restores 2 blocks/CU (512 blocks).
__global__ void __launch_bounds__(256, 2) gemm_w2(const u16* __restrict__ A,
                                                  const u16* __restrict__ Bt,
                                                  float* __restrict__ C0,
                                                  u16* __restrict__ C1) {
  __shared__ u16 sA[128][64];
  __shared__ u16 sB[128][64];
  const int K = 4096, N = 1024;
  const int z = blockIdx.z, koff = z * 2048;
  const int tid = threadIdx.x;
  const int w = tid >> 6, lane = tid & 63;
  const int g = lane >> 4, l15 = lane & 15;
  const int r8 = lane >> 3, c8 = lane & 7;
  const int bm = blockIdx.y * 128, bn = blockIdx.x * 128;

  f32x4 acc[4][4];
#pragma unroll
  for (int i = 0; i < 4; ++i)
#pragma unroll
    for (int j = 0; j < 4; ++j) acc[i][j] = (f32x4){0.f, 0.f, 0.f, 0.f};

  const u16* Ag = A + (size_t)(bm + w * 32 + r8) * K + koff + (c8 ^ r8) * 8;
  const u16* Bg = Bt + (size_t)(bn + w * 32 + r8) * K + koff + (c8 ^ r8) * 8;
  const int mrow = (w >> 1) * 64, ncol = (w & 1) * 64;
  const int swz = l15 & 7;

  for (int k0 = 0; k0 < 2048; k0 += 64) {
#pragma unroll
    for (int t = 0; t < 4; ++t) {
      async16(&sA[w * 32 + t * 8][0], Ag + (size_t)(t * 8) * K + k0);
      async16(&sB[w * 32 + t * 8][0], Bg + (size_t)(t * 8) * K + k0);
    }
    __syncthreads();
#pragma unroll
    for (int kk = 0; kk < 2; ++kk) {
      const int cb = ((kk * 4 + g) ^ swz) * 8;
      bf16x8 a[4], b[4];
#pragma unroll
      for (int i = 0; i < 4; ++i) {
        a[i] = *(const bf16x8*)&sA[mrow + i * 16 + l15][cb];
        b[i] = *(const bf16x8*)&sB[ncol + i * 16 + l15][cb];
      }
#pragma unroll
      for (int mi = 0; mi < 4; ++mi)
#pragma unroll
        for (int ni = 0; ni < 4; ++ni)
          acc[mi][ni] = __builtin_amdgcn_mfma_f32_16x16x32_bf16(a[mi], b[ni], acc[mi][ni], 0, 0, 0);
    }
    __syncthreads();
  }
#pragma unroll
  for (int mi = 0; mi < 4; ++mi)
#pragma unroll
    for (int ni = 0; ni < 4; ++ni)
#pragma unroll
      for (int r = 0; r < 4; ++r) {
        size_t idx = (size_t)(bm + mrow + mi * 16 + g * 4 + r) * N + bn + ncol + ni * 16 + l15;
        if (z == 0) C0[idx] = acc[mi][ni][r];
        else        C1[idx] = f2bf(acc[mi][ni][r]);
      }
}

__global__ void __launch_bounds__(256) w2_combine(float* __restrict__ out,
                                                  const u16* __restrict__ P1) {
  int idx = (blockIdx.x * 256 + threadIdx.x) * 4;
  float4 v = *(const float4*)(out + idx);
  union { uint2 q; u16 s[4]; } p;
  p.q = *(const uint2*)(P1 + idx);
  v.x += bf2f(p.s[0]); v.y += bf2f(p.s[1]);
  v.z += bf2f(p.s[2]); v.w += bf2f(p.s[3]);
  *(float4*)(out + idx) = v;
}

// ---------------- Flash attention (causal, GQA 16q/4kv, D=64) ----------------
// 128-row q-tile pairs (t0=pr, t1=31-pr) x kv-parity split: 512 equal blocks.
__global__ void __launch_bounds__(256, 2) attn(const u16* __restrict__ Q,
                                               const u16* __restrict__ K,
                                               const u16* __restrict__ Vt,
                                               u16* __restrict__ O0,
                                               u16* __restrict__ O1,
                                               float* __restrict__ L0,
                                               float* __restrict__ L1) {
  __shared__ u16 sK[2][64][64];
  __shared__ u16 sV[2][64][64];     // sV[b][d][kv]
  __shared__ u16 sP[4][64][68];     // [wave][half*32+mi*16+q16][kv] pad+4
  const int pr = blockIdx.x >> 1;
  const int split = blockIdx.x & 1;
  const int h = blockIdx.y;
  const int kvh = h >> 2;
  const int tid = threadIdx.x;
  const int w = tid >> 6, lane = tid & 63;
  const int g = lane >> 4, l15 = lane & 15;
  const int r8 = lane >> 3, c8 = lane & 7;
  const int swz = l15 & 7;
  const int t0 = pr, t1 = 31 - pr;
  const int off = split * 64;

  u16* Op = split ? O1 : O0;
  float* Lp = split ? L1 : L0;

  bf16x8 qf[2][2][2];
  {
    const u16* Qh = Q + (size_t)h * T_SEQ * 64;
#pragma unroll
    for (int half = 0; half < 2; ++half)
#pragma unroll
      for (int mi = 0; mi < 2; ++mi) {
        const int q = (half ? t1 : t0) * 128 + w * 32 + mi * 16 + l15;
#pragma unroll
        for (int kk = 0; kk < 2; ++kk)
          qf[half][mi][kk] = *(const bf16x8*)(Qh + (size_t)q * 64 + (kk * 4 + g) * 8);
      }
  }

  f32x4 oacc[2][2][4];
  f32x4 lacc[2][2];
#pragma unroll
  for (int half = 0; half < 2; ++half)
#pragma unroll
    for (int mi = 0; mi < 2; ++mi) {
      lacc[half][mi] = (f32x4){0.f, 0.f, 0.f, 0.f};
#pragma unroll
      for (int nd = 0; nd < 4; ++nd) oacc[half][mi][nd] = (f32x4){0.f, 0.f, 0.f, 0.f};
    }

  bf16x8 ONES;
  {
    union { u16 s[8]; bf16x8 v; } o;
#pragma unroll
    for (int i = 0; i < 8; ++i) o.s[i] = 0x3F80;  // bf16 1.0
    ONES = o.v;
  }

  const u16* Kg = K + ((size_t)kvh * T_SEQ + w * 16 + r8) * 64 + (c8 ^ r8) * 8;
  const u16* Vg = Vt + ((size_t)kvh * 64 + w * 16 + r8) * T_SEQ + (c8 ^ r8) * 8;

#define STAGE(J, B)                                                     \
  {                                                                     \
    const int kv0_ = (J) * 64;                                          \
    async16(&sK[B][w * 16 + 0][0], Kg + (size_t)kv0_ * 64);             \
    async16(&sK[B][w * 16 + 8][0], Kg + (size_t)(kv0_ + 8) * 64);       \
    async16(&sV[B][w * 16 + 0][0], Vg + kv0_);                          \
    async16(&sV[B][w * 16 + 8][0], Vg + (size_t)8 * T_SEQ + kv0_);      \
  }

#define BODY(B, ACT0, M0, M1)                                                     \
  {                                                                               \
    const int b_ = (B);                                                           \
    f32x4 s1[2][4], s0[2][4];                                                     \
    _Pragma("unroll") for (int mi = 0; mi < 2; ++mi)                              \
    _Pragma("unroll") for (int kt = 0; kt < 4; ++kt) {                            \
      s1[mi][kt] = (f32x4){0.f, 0.f, 0.f, 0.f};                                   \
      if (ACT0) s0[mi][kt] = (f32x4){0.f, 0.f, 0.f, 0.f};                         \
    }                                                                             \
    _Pragma("unroll") for (int kt = 0; kt < 4; ++kt)                              \
    _Pragma("unroll") for (int kk = 0; kk < 2; ++kk) {                            \
      bf16x8 kf = *(const bf16x8*)&sK[b_][kt * 16 + l15][((kk * 4 + g) ^ swz) * 8]; \
      _Pragma("unroll") for (int mi = 0; mi < 2; ++mi) {                          \
        s1[mi][kt] = __builtin_amdgcn_mfma_f32_16x16x32_bf16(kf, qf[1][mi][kk], s1[mi][kt], 0, 0, 0); \
        if (ACT0)                                                                 \
          s0[mi][kt] = __builtin_amdgcn_mfma_f32_16x16x32_bf16(kf, qf[0][mi][kk], s0[mi][kt], 0, 0, 0); \
      }                                                                           \
    }                                                                             \
    _Pragma("unroll") for (int mi = 0; mi < 2; ++mi) {                            \
      const int thr_ = w * 32 + mi * 16 + l15 - off;                              \
      _Pragma("unroll") for (int kt = 0; kt < 4; ++kt) {                          \
        float p_[4];                                                              \
        _Pragma("unroll") for (int r = 0; r < 4; ++r) {                           \
          float p = fexp2(s1[mi][kt][r]);                                         \
          if (M1 && (kt * 16 + g * 4 + r > thr_)) p = 0.f;                        \
          p_[r] = p;                                                              \
        }                                                                         \
        uint2 pk;                                                                 \
        pk.x = pack_bf16(p_[0], p_[1]);                                           \
        pk.y = pack_bf16(p_[2], p_[3]);                                           \
        *(uint2*)&sP[w][32 + mi * 16 + l15][kt * 16 + g * 4] = pk;                \
      }                                                                           \
      if (ACT0) {                                                                 \
        _Pragma("unroll") for (int kt = 0; kt < 4; ++kt) {                        \
          float p_[4];                                                            \
          _Pragma("unroll") for (int r = 0; r < 4; ++r) {                         \
            float p = fexp2(s0[mi][kt][r]);                                       \
            if (M0 && (kt * 16 + g * 4 + r > thr_)) p = 0.f;                      \
            p_[r] = p;                                                            \
          }                                                                       \
          uint2 pk;                                                               \
          pk.x = pack_bf16(p_[0], p_[1]);                                         \
          pk.y = pack_bf16(p_[2], p_[3]);                                         \
          *(uint2*)&sP[w][mi * 16 + l15][kt * 16 + g * 4] = pk;                   \
        }                                                                         \
      }                                                                           \
    }                                                                             \
    __builtin_amdgcn_wave_barrier(); /* sP per-wave; order write->read */         \
    _Pragma("unroll") for (int kk = 0; kk < 2; ++kk) {                            \
      bf16x8 pf1[2], pf0[2];                                                      \
      _Pragma("unroll") for (int mi = 0; mi < 2; ++mi) {                          \
        pf1[mi] = *(const bf16x8*)&sP[w][32 + mi * 16 + l15][kk * 32 + g * 8];    \
        if (ACT0) pf0[mi] = *(const bf16x8*)&sP[w][mi * 16 + l15][kk * 32 + g * 8]; \
      }                                                                           \
      _Pragma("unroll") for (int mi = 0; mi < 2; ++mi) {                          \
        lacc[1][mi] = __builtin_amdgcn_mfma_f32_16x16x32_bf16(pf1[mi], ONES, lacc[1][mi], 0, 0, 0); \
        if (ACT0)                                                                 \
          lacc[0][mi] = __builtin_amdgcn_mfma_f32_16x16x32_bf16(pf0[mi], ONES, lacc[0][mi], 0, 0, 0); \
      }                                                                           \
      _Pragma("unroll") for (int nd = 0; nd < 4; ++nd) {                          \
        bf16x8 vf = *(const bf16x8*)&sV[b_][nd * 16 + l15][((kk * 4 + g) ^ swz) * 8]; \
        _Pragma("unroll") for (int mi = 0; mi < 2; ++mi) {                        \
          oacc[1][mi][nd] = __builtin_amdgcn_mfma_f32_16x16x32_bf16(pf1[mi], vf, oacc[1][mi][nd], 0, 0, 0); \
          if (ACT0)                                                               \
            oacc[0][mi][nd] = __builtin_amdgcn_mfma_f32_16x16x32_bf16(pf0[mi], vf, oacc[0][mi][nd], 0, 0, 0); \
        }                                                                         \
      }                                                                           \
    }                                                                             \
  }

  const int e0 = 2 * t0 + split, e1 = 2 * t1 + split;
  STAGE(split, 0);
  int jj = split, b = 0;
  for (; jj < e0; jj += 2, b ^= 1) {   // both halves, no mask
    __syncthreads();
    STAGE(jj + 2, b ^ 1);
    BODY(b, true, false, false);
  }
  {                                     // jj == e0: dual, mask half0
    __syncthreads();
    STAGE(jj + 2, b ^ 1);               // e0+2 <= e1 always (t1 >= t0+1)
    BODY(b, true, true, false);
    jj += 2; b ^= 1;
  }
  for (; jj < e1; jj += 2, b ^= 1) {   // half1 only
    __syncthreads();
    STAGE(jj + 2, b ^ 1);
    BODY(b, false, false, false);
  }
  {                                     // jj == e1: half1, mask
    __syncthreads();
    BODY(b, false, false, true);
  }
#undef STAGE
#undef BODY

  // epilogue: write UNNORMALIZED partial O (bf16) + partial l (f32)
#pragma unroll
  for (int half = 0; half < 2; ++half) {
    const int tb = (half ? t1 : t0) * 128;
#pragma unroll
    for (int mi = 0; mi < 2; ++mi)
#pragma unroll
      for (int r = 0; r < 4; ++r) {
        const int trow = tb + w * 32 + mi * 16 + g * 4 + r;
#pragma unroll
        for (int nd = 0; nd < 4; ++nd)
          Op[(size_t)trow * DMODEL + h * 64 + nd * 16 + l15] = f2bf(oacc[half][mi][nd][r]);
        if (l15 == 0) Lp[h * T_SEQ + trow] = lacc[half][mi][r];
      }
  }
}

// ---------------- combine partials: AO = (O0+O1)/(l0+l1) ----------------
__global__ void __launch_bounds__(256) attn_combine(const u16* __restrict__ O0,
                                                    const u16* __restrict__ O1,
                                                    const float* __restrict__ L0,
                                                    const float* __restrict__ L1,
                                                    u16* __restrict__ AO) {
  const int t = blockIdx.x, tid = threadIdx.x;
  const int h = tid >> 4, d4 = (tid & 15) * 4;
  const float inv = 1.f / (L0[h * T_SEQ + t] + L1[h * T_SEQ + t]);
  const size_t idx = (size_t)t * DMODEL + h * 64 + d4;
  union { uint2 q; u16 s[4]; } a, b, o;
  a.q = *(const uint2*)(O0 + idx);
  b.q = *(const uint2*)(O1 + idx);
#pragma unroll
  for (int i = 0; i < 4; ++i) o.s[i] = f2bf((bf2f(a.s[i]) + bf2f(b.s[i])) * inv);
  *(uint2*)(AO + idx) = o.q;
}

// ---------------------------------------------------------------------------
extern "C" void kernel_launch(void* const* d_in, const int* in_sizes, int n_in,
                              void* d_out, int out_size, void* d_ws, size_t ws_size,
                              hipStream_t stream) {
  const float* query = (const float*)d_in[0];
  const float* Wq = (const float*)d_in[1];
  const float* Wk = (const float*)d_in[2];
  const float* Wv = (const float*)d_in[3];
  const float* W1 = (const float*)d_in[4];
  const float* W2 = (const float*)d_in[5];
  float* out = (float*)d_out;

  char* ws = (char*)d_ws;
  size_t off = 0;
  auto alloc = [&](size_t bytes) { char* p = ws + off; off += (bytes + 255) & ~(size_t)255; return p; };
  // Region A (32 MB) -- all dead after attention; H aliases it.
  u16* Xb   = (u16*)alloc((size_t)4096 * 1024 * 2);
  u16* QKVb = (u16*)alloc((size_t)4096 * 1536 * 2);
  u16* Qb   = (u16*)alloc((size_t)16 * 4096 * 64 * 2);
  u16* Kb   = (u16*)alloc((size_t)4 * 4096 * 64 * 2);
  u16* Vtb  = (u16*)alloc((size_t)4 * 4096 * 64 * 2);
  u16* H    = (u16*)ws;  // [4096][4096] bf16 = 32 MB, aliases region A
  // Attention partials alias Xb / QKVb (dead by the time attn runs):
  u16*   O0p = Xb;                               // 8 MB
  u16*   O1p = QKVb;                             // 8 MB
  float* L0p = (float*)(QKVb + (size_t)4096 * 1024);  // 256 KB
  float* L1p = L0p + 16 * T_SEQ;                      // 256 KB
  // Region B
  u16* WqkvT = (u16*)alloc((size_t)1536 * 1024 * 2);
  u16* W1T   = (u16*)alloc((size_t)4096 * 1024 * 2);
  u16* W2T   = (u16*)alloc((size_t)1024 * 4096 * 2);
  u16* AO    = (u16*)alloc((size_t)4096 * 1024 * 2);
  u16* P1    = W1T;  // W2 split-K bf16 partial, aliases dead W1T (8 MB)
  (void)ws_size; (void)in_sizes; (void)n_in; (void)out_size;

  prep<<<6528, 256, 0, stream>>>(query, Wq, Wk, Wv, W1, W2, Xb, WqkvT, W1T, W2T);
  gemm_bt<2, 0, u16><<<dim3(12, 64), 256, 0, stream>>>(Xb, WqkvT, QKVb, 4096, 1536, 1024);
  rope_vt<<<4352, 256, 0, stream>>>(QKVb, Qb, Kb, Vtb);
  attn<<<dim3(32, 16), 256, 0, stream>>>(Qb, Kb, Vtb, O0p, O1p, L0p, L1p);
  attn_combine<<<4096, 256, 0, stream>>>(O0p, O1p, L0p, L1p, AO);
  gemm_bt<4, 1, u16><<<dim3(32, 32), 256, 0, stream>>>(AO, W1T, H, 4096, 4096, 1024);
  gemm_w2<<<dim3(8, 32, 2), 256, 0, stream>>>(H, W2T, out, P1);
  w2_combine<<<4096, 256, 0, stream>>>(out, P1);
}